// Round 2
// baseline (201.303 us; speedup 1.0000x reference)
//
#include <hip/hip_runtime.h>

// Max-unpool 2x2 (stride 2, non-overlapping windows).
// x:     [N=32, C=64, H=64, W=64] fp32
// where: same shape, int32 in [0,4): pos = sy*2 + sx
// out:   [N, C, 128, 128] fp32; out[n,c,2h+sy,2w+sx] = (where==pos) ? x : 0
//
// One thread per 4 consecutive input pixels: float4/int4 loads (16 B/lane),
// four nontemporal float4 stores (two per output row). Windows are
// non-overlapping so every output element is written exactly once -> no
// zero-init pass needed despite the 0xAA poison. Nontemporal stores skip L2
// write-allocate (output is write-once, never re-read).

typedef float v4f __attribute__((ext_vector_type(4)));
typedef int   v4i __attribute__((ext_vector_type(4)));

__global__ __launch_bounds__(256) void WhatWhereUnPooling2D_51522427683437_kernel(
    const float* __restrict__ x,
    const int* __restrict__ where,
    float* __restrict__ out,
    int n_quads) {
    int tid = blockIdx.x * blockDim.x + threadIdx.x;
    if (tid >= n_quads) return;

    // Input geometry: W=64 -> 16 quads/row, H=64 rows, N*C=2048 planes.
    int q   = tid & 15;        // quad index within row: w = 4*q
    int rem = tid >> 4;
    int h   = rem & 63;
    int nc  = rem >> 6;

    int in_off = ((nc << 6) + h) * 64 + (q << 2);
    v4f xv = *reinterpret_cast<const v4f*>(x + in_off);
    v4i wv = *reinterpret_cast<const v4i*>(where + in_off);

    // Row 2h (sy=0): positions 0,1 ; Row 2h+1 (sy=1): positions 2,3.
    v4f r0a, r0b, r1a, r1b;
    r0a.x = (wv.x == 0) ? xv.x : 0.0f;
    r0a.y = (wv.x == 1) ? xv.x : 0.0f;
    r0a.z = (wv.y == 0) ? xv.y : 0.0f;
    r0a.w = (wv.y == 1) ? xv.y : 0.0f;
    r0b.x = (wv.z == 0) ? xv.z : 0.0f;
    r0b.y = (wv.z == 1) ? xv.z : 0.0f;
    r0b.z = (wv.w == 0) ? xv.w : 0.0f;
    r0b.w = (wv.w == 1) ? xv.w : 0.0f;

    r1a.x = (wv.x == 2) ? xv.x : 0.0f;
    r1a.y = (wv.x == 3) ? xv.x : 0.0f;
    r1a.z = (wv.y == 2) ? xv.y : 0.0f;
    r1a.w = (wv.y == 3) ? xv.y : 0.0f;
    r1b.x = (wv.z == 2) ? xv.z : 0.0f;
    r1b.y = (wv.z == 3) ? xv.z : 0.0f;
    r1b.z = (wv.w == 2) ? xv.w : 0.0f;
    r1b.w = (wv.w == 3) ? xv.w : 0.0f;

    // Output: OH=128, OW=128. Base = (nc*128 + 2h)*128 + 8*q.
    int out_off = (((nc << 7) + (h << 1)) << 7) + (q << 3);
    v4f* o0 = reinterpret_cast<v4f*>(out + out_off);
    v4f* o1 = reinterpret_cast<v4f*>(out + out_off + 128);
    __builtin_nontemporal_store(r0a, o0);
    __builtin_nontemporal_store(r0b, o0 + 1);
    __builtin_nontemporal_store(r1a, o1);
    __builtin_nontemporal_store(r1b, o1 + 1);
}

extern "C" void kernel_launch(void* const* d_in, const int* in_sizes, int n_in,
                              void* d_out, int out_size, void* d_ws, size_t ws_size,
                              hipStream_t stream) {
    const float* x     = (const float*)d_in[0];
    const int*   where = (const int*)d_in[1];
    float*       out   = (float*)d_out;

    int n_elems = in_sizes[0];          // 32*64*64*64 = 8388608
    int n_quads = n_elems >> 2;         // 2097152 threads
    int block = 256;
    int grid = (n_quads + block - 1) / block;  // 8192 blocks

    WhatWhereUnPooling2D_51522427683437_kernel<<<grid, block, 0, stream>>>(
        x, where, out, n_quads);
}

// Round 3
// 185.736 us; speedup vs baseline: 1.0838x; 1.0838x over previous
//
#include <hip/hip_runtime.h>

// Max-unpool 2x2 (stride 2, non-overlapping windows).
// x:     [N=32, C=64, H=64, W=64] fp32
// where: same shape, int32 in [0,4): pos = sy*2 + sx
// out:   [N, C, 128, 128] fp32; out[n,c,2h+sy,2w+sx] = (where==pos) ? x : 0
//
// One thread per 4 consecutive input pixels: float4/int4 loads (16 B/lane),
// four REGULAR float4 stores (two per output row). Windows are non-overlapping
// so every output element is written exactly once -> no zero-init pass needed
// despite the 0xAA poison.
//
// NOTE (round 2 post-mortem): nontemporal stores regressed +21us — the 256 MiB
// output fits in the 256 MiB Infinity Cache, and regular write-back stores are
// absorbed by L3 within the timed window; NT bypasses L3 and forces synchronous
// HBM writes. Keep regular stores.

typedef float v4f __attribute__((ext_vector_type(4)));
typedef int   v4i __attribute__((ext_vector_type(4)));

__global__ __launch_bounds__(256) void WhatWhereUnPooling2D_51522427683437_kernel(
    const float* __restrict__ x,
    const int* __restrict__ where,
    float* __restrict__ out,
    int n_quads) {
    int tid = blockIdx.x * blockDim.x + threadIdx.x;
    if (tid >= n_quads) return;

    // Input geometry: W=64 -> 16 quads/row, H=64 rows, N*C=2048 planes.
    int q   = tid & 15;        // quad index within row: w = 4*q
    int rem = tid >> 4;
    int h   = rem & 63;
    int nc  = rem >> 6;

    int in_off = ((nc << 6) + h) * 64 + (q << 2);
    v4f xv = *reinterpret_cast<const v4f*>(x + in_off);
    v4i wv = *reinterpret_cast<const v4i*>(where + in_off);

    // Row 2h (sy=0): positions 0,1 ; Row 2h+1 (sy=1): positions 2,3.
    v4f r0a, r0b, r1a, r1b;
    r0a.x = (wv.x == 0) ? xv.x : 0.0f;
    r0a.y = (wv.x == 1) ? xv.x : 0.0f;
    r0a.z = (wv.y == 0) ? xv.y : 0.0f;
    r0a.w = (wv.y == 1) ? xv.y : 0.0f;
    r0b.x = (wv.z == 0) ? xv.z : 0.0f;
    r0b.y = (wv.z == 1) ? xv.z : 0.0f;
    r0b.z = (wv.w == 0) ? xv.w : 0.0f;
    r0b.w = (wv.w == 1) ? xv.w : 0.0f;

    r1a.x = (wv.x == 2) ? xv.x : 0.0f;
    r1a.y = (wv.x == 3) ? xv.x : 0.0f;
    r1a.z = (wv.y == 2) ? xv.y : 0.0f;
    r1a.w = (wv.y == 3) ? xv.y : 0.0f;
    r1b.x = (wv.z == 2) ? xv.z : 0.0f;
    r1b.y = (wv.z == 3) ? xv.z : 0.0f;
    r1b.z = (wv.w == 2) ? xv.w : 0.0f;
    r1b.w = (wv.w == 3) ? xv.w : 0.0f;

    // Output: OH=128, OW=128. Base = (nc*128 + 2h)*128 + 8*q.
    int out_off = (((nc << 7) + (h << 1)) << 7) + (q << 3);
    *reinterpret_cast<v4f*>(out + out_off)           = r0a;
    *reinterpret_cast<v4f*>(out + out_off + 4)       = r0b;
    *reinterpret_cast<v4f*>(out + out_off + 128)     = r1a;
    *reinterpret_cast<v4f*>(out + out_off + 128 + 4) = r1b;
}

extern "C" void kernel_launch(void* const* d_in, const int* in_sizes, int n_in,
                              void* d_out, int out_size, void* d_ws, size_t ws_size,
                              hipStream_t stream) {
    const float* x     = (const float*)d_in[0];
    const int*   where = (const int*)d_in[1];
    float*       out   = (float*)d_out;

    int n_elems = in_sizes[0];          // 32*64*64*64 = 8388608
    int n_quads = n_elems >> 2;         // 2097152 threads
    int block = 256;
    int grid = (n_quads + block - 1) / block;  // 8192 blocks

    WhatWhereUnPooling2D_51522427683437_kernel<<<grid, block, 0, stream>>>(
        x, where, out, n_quads);
}

// Round 4
// 181.476 us; speedup vs baseline: 1.1093x; 1.0235x over previous
//
#include <hip/hip_runtime.h>

// Max-unpool 2x2 (stride 2, non-overlapping windows).
// x:     [N=32, C=64, H=64, W=64] fp32
// where: same shape, int32 in [0,4): pos = sy*2 + sx
// out:   [N, C, 128, 128] fp32; out[n,c,2h+sy,2w+sx] = (where==pos) ? x : 0
//
// Layout (round-3 post-mortem): one thread per PAIR of consecutive input
// pixels. Each thread stores one float4 to output row 2h and one to 2h+1;
// consecutive lanes -> consecutive float4 in the same row = perfectly
// contiguous 1 KiB/wave store instructions. The 4-px/thread variant (round 3)
// made each store instruction 32B-strided across lanes and was ~5us slower.
// Stores are 2/3 of traffic (128 MiB of 192 MiB) so store contiguity wins
// over wider loads.
//
// Round-2 post-mortem: nontemporal stores regressed +21us (output is
// L3-resident in the timed window; NT bypasses the 256 MiB Infinity Cache
// and forces synchronous HBM writes). Regular write-back stores.
//
// Windows are non-overlapping: every output element written exactly once,
// so no zero-init pass is needed despite the 0xAA poison.

__global__ __launch_bounds__(256) void WhatWhereUnPooling2D_51522427683437_kernel(
    const float* __restrict__ x,
    const int* __restrict__ where,
    float* __restrict__ out) {
    int tid = blockIdx.x * blockDim.x + threadIdx.x;   // grid covers exactly n_pairs

    // Input geometry: W=64 -> 32 pairs/row, H=64 rows, N*C=2048 planes.
    int w2  = tid & 31;        // pair index within row: w = 2*w2
    int rem = tid >> 5;
    int h   = rem & 63;
    int nc  = rem >> 6;

    int in_off = ((nc << 6) + h) * 64 + (w2 << 1);   // (nc*64 + h)*64 + 2*w2
    float2 xv = *reinterpret_cast<const float2*>(x + in_off);
    int2   wv = *reinterpret_cast<const int2*>(where + in_off);

    // Row 2h (sy=0): positions 0 (sx=0), 1 (sx=1)
    float4 r0;
    r0.x = (wv.x == 0) ? xv.x : 0.0f;
    r0.y = (wv.x == 1) ? xv.x : 0.0f;
    r0.z = (wv.y == 0) ? xv.y : 0.0f;
    r0.w = (wv.y == 1) ? xv.y : 0.0f;
    // Row 2h+1 (sy=1): positions 2, 3
    float4 r1;
    r1.x = (wv.x == 2) ? xv.x : 0.0f;
    r1.y = (wv.x == 3) ? xv.x : 0.0f;
    r1.z = (wv.y == 2) ? xv.y : 0.0f;
    r1.w = (wv.y == 3) ? xv.y : 0.0f;

    // Output: OH=128, OW=128. Base = (nc*128 + 2h)*128 + 4*w2.
    int out_off = (((nc << 7) + (h << 1)) << 7) + (w2 << 2);
    *reinterpret_cast<float4*>(out + out_off)       = r0;
    *reinterpret_cast<float4*>(out + out_off + 128) = r1;
}

extern "C" void kernel_launch(void* const* d_in, const int* in_sizes, int n_in,
                              void* d_out, int out_size, void* d_ws, size_t ws_size,
                              hipStream_t stream) {
    const float* x     = (const float*)d_in[0];
    const int*   where = (const int*)d_in[1];
    float*       out   = (float*)d_out;

    int n_elems = in_sizes[0];          // 32*64*64*64 = 8388608
    int n_pairs = n_elems >> 1;         // 4194304 threads
    int block = 256;
    int grid = n_pairs / block;         // 16384 blocks, exact

    WhatWhereUnPooling2D_51522427683437_kernel<<<grid, block, 0, stream>>>(
        x, where, out);
}